// Round 8
// baseline (250.565 us; speedup 1.0000x reference)
//
#include <hip/hip_runtime.h>

#define B_    4
#define DEC_  256
#define ENC_  1024
#define D_    1024
#define A_    144
#define V_    50257
#define NROW_ (B_ * DEC_)
#define NPAIR_ ((NROW_ * ENC_) / 2)     // 524,288 position pairs

typedef __attribute__((ext_vector_type(4))) float float4v;

// ---------------- kernel 1: p_gen = sigmoid(hidden . W_pgen + b) -> out tail (fp32) ----------------
__global__ void k_pgen(const float* __restrict__ hid, const float* __restrict__ Wp,
                       const float* __restrict__ bp, float* __restrict__ tail){
  int row = blockIdx.x, t = threadIdx.x;
  float4v hv = reinterpret_cast<const float4v*>(hid + (size_t)row * D_)[t];
  float4v wv = reinterpret_cast<const float4v*>(Wp)[t];
  float s = hv[0]*wv[0] + hv[1]*wv[1] + hv[2]*wv[2] + hv[3]*wv[3];
  for (int o = 32; o > 0; o >>= 1) s += __shfl_down(s, o, 64);
  __shared__ float red[4];
  if ((t & 63) == 0) red[t >> 6] = s;
  __syncthreads();
  if (t == 0){
    float tot = red[0] + red[1] + red[2] + red[3] + bp[0];
    tail[row] = 1.f / (1.f + __expf(-tot));
  }
}

// ---------------- kernel 2: out = p_gen * ovp (fp32, 4-wide, grid-stride) ----------------
__global__ void k_base(const float* __restrict__ ovp, const float* __restrict__ tail,
                       float* __restrict__ out){
  const unsigned N4 = (unsigned)(((size_t)NROW_ * V_) / 4);   // 51,463,168 / 4 exact
  unsigned stride = gridDim.x * blockDim.x;
  for (unsigned vi = blockIdx.x * blockDim.x + threadIdx.x; vi < N4; vi += stride){
    unsigned i0 = vi * 4u;
    unsigned r0 = i0 / (unsigned)V_;
    unsigned r1 = (i0 + 3u) / (unsigned)V_;
    float4v a = reinterpret_cast<const float4v*>(ovp)[vi];
    float4v o;
    float pg0 = tail[r0];
    if (r0 == r1){
#pragma unroll
      for (int k = 0; k < 4; ++k) o[k] = pg0 * a[k];
    } else {
      float pg1 = tail[r1];
      unsigned bnd = r1 * (unsigned)V_;
#pragma unroll
      for (int k = 0; k < 4; ++k)
        o[k] = (((i0 + (unsigned)k) < bnd) ? pg0 : pg1) * a[k];
    }
    reinterpret_cast<float4v*>(out)[vi] = o;
  }
}

// ---------------- kernel 3: scatter-add, 8 lanes per position-PAIR ----------------
// A pair = 2 positions = 1152 B = 9 aligned 128B lines. Each of 9 steps: 8 lanes
// load one full 128B line (float4 each) -> 100% line utilization by construction.
// accA = pos0 partial dot, accB = pos1; step 4 straddles the boundary (static split).
// 3x shfl_xor butterfly within the 8-lane group; lanes 0/1 issue the two atomics.
__global__ __launch_bounds__(256) void k_scat(const int* __restrict__ ids,
                                              const float* __restrict__ att,
                                              const float* __restrict__ Wa,
                                              const float* __restrict__ ba,
                                              const float* __restrict__ tail,
                                              float* __restrict__ out){
  __shared__ float sW[A_];
  int t = threadIdx.x;
  if (t < A_) sW[t] = Wa[t];
  __syncthreads();

  unsigned gtid = blockIdx.x * 256u + t;
  unsigned pair = gtid >> 3;                  // 0 .. NPAIR_-1
  unsigned l8   = t & 7u;
  unsigned pos0 = pair << 1;
  unsigned row  = pos0 >> 10;                 // / ENC_
  unsigned e0   = pos0 & (ENC_ - 1);
  unsigned b    = row >> 8;                   // / DEC_

  const float4v* ap = reinterpret_cast<const float4v*>(att + (size_t)pair * (2 * A_));
  float accA = 0.f, accB = 0.f;

#pragma unroll
  for (int j = 0; j < 4; ++j){                // floats 0..127  -> pos0, w[0..127]
    float4v v = ap[8*j + l8];
    const float* w = &sW[32*j + 4*l8];
    accA += v[0]*w[0] + v[1]*w[1] + v[2]*w[2] + v[3]*w[3];
  }
  {                                            // straddle step: floats 128..159
    float4v v = ap[32 + l8];
    const float* w = (l8 < 4) ? &sW[128 + 4*l8] : &sW[4*(l8 - 4)];
    float p = v[0]*w[0] + v[1]*w[1] + v[2]*w[2] + v[3]*w[3];
    if (l8 < 4) accA += p; else accB += p;
  }
#pragma unroll
  for (int j = 5; j < 9; ++j){                // floats 160..287 -> pos1, w[16..143]
    float4v v = ap[8*j + l8];
    const float* w = &sW[32*j + 4*l8 - 144];
    accB += v[0]*w[0] + v[1]*w[1] + v[2]*w[2] + v[3]*w[3];
  }

#pragma unroll
  for (int m = 1; m < 8; m <<= 1){
    accA += __shfl_xor(accA, m, 64);
    accB += __shfl_xor(accB, m, 64);
  }

  if (l8 < 2){
    float acc = (l8 == 0) ? accA : accB;
    float pg = tail[row];
    float x = acc + ba[0];
    x = x > 0.f ? x : 0.f;
    float val = (1.f - pg) * x;
    int id = ids[b * ENC_ + e0 + l8];
    unsafeAtomicAdd(out + (size_t)row * V_ + id, val);   // global_atomic_add_f32
  }
}

extern "C" void kernel_launch(void* const* d_in, const int* in_sizes, int n_in,
                              void* d_out, int out_size, void* d_ws, size_t ws_size,
                              hipStream_t stream) {
  (void)in_sizes; (void)n_in; (void)d_ws; (void)ws_size; (void)out_size;
  const int*   ids = (const int*)  d_in[0];
  const float* att = (const float*)d_in[1];
  const float* hid = (const float*)d_in[2];
  const float* ovp = (const float*)d_in[3];
  const float* Wp  = (const float*)d_in[4];
  const float* bp  = (const float*)d_in[5];
  const float* Wa  = (const float*)d_in[6];
  const float* ba  = (const float*)d_in[7];
  float* out  = (float*)d_out;
  float* tail = out + (size_t)NROW_ * V_;   // p_gen output (fp32)

  k_pgen<<<NROW_, 256, 0, stream>>>(hid, Wp, bp, tail);
  k_base<<<4096,  256, 0, stream>>>(ovp, tail, out);
  k_scat<<<(NPAIR_ * 8) / 256, 256, 0, stream>>>(ids, att, Wa, ba, tail, out);
}

// Round 9
// 206.880 us; speedup vs baseline: 1.2112x; 1.2112x over previous
//
#include <hip/hip_runtime.h>

#define B_    4
#define DEC_  256
#define ENC_  1024
#define D_    1024
#define A_    144
#define V_    50257
#define NROW_ (B_ * DEC_)
#define CH_   8          // vocab chunks per row
#define CW_   6288       // chunk width (multiple of 8; 8*6288 = 50304 >= V_)

typedef __attribute__((ext_vector_type(4))) float float4v;

// ---------------- kernel 1: p_gen = sigmoid(hidden . W_pgen + b) -> out tail (fp32) ----------------
__global__ void k_pgen(const float* __restrict__ hid, const float* __restrict__ Wp,
                       const float* __restrict__ bp, float* __restrict__ tail){
  int row = blockIdx.x, t = threadIdx.x;
  float4v hv = reinterpret_cast<const float4v*>(hid + (size_t)row * D_)[t];
  float4v wv = reinterpret_cast<const float4v*>(Wp)[t];
  float s = hv[0]*wv[0] + hv[1]*wv[1] + hv[2]*wv[2] + hv[3]*wv[3];
  for (int o = 32; o > 0; o >>= 1) s += __shfl_down(s, o, 64);
  __shared__ float red[4];
  if ((t & 63) == 0) red[t >> 6] = s;
  __syncthreads();
  if (t == 0){
    float tot = red[0] + red[1] + red[2] + red[3] + bp[0];
    tail[row] = 1.f / (1.f + __expf(-tot));
  }
}

// ---------------- kernel 2: fused copy-logit scatter + base stream ----------------
// block = (row, chunk): chunk covers vocab [q0, q0+qlen). Phases:
//  A: zero LDS add-array; scan row's 1024 ids, list those in-chunk
//  B: att-dot for listed e's (4 lanes/e) -> ds_add_f32 into LDS add-array
//  C: stream out[row, q0:q0+qlen] = pg*ovp + ldsAdd  (float4, no atomics, no RMW)
__global__ __launch_bounds__(256) void k_merge(const int* __restrict__ ids,
                                               const float* __restrict__ att,
                                               const float* __restrict__ ovp,
                                               const float* __restrict__ Wa,
                                               const float* __restrict__ ba,
                                               const float* __restrict__ tail,
                                               float* __restrict__ out){
  __shared__ float    sW[A_];
  __shared__ float    sAdd[CW_ + 8];
  __shared__ unsigned sList[ENC_];
  __shared__ int      sCnt;

  int t = threadIdx.x;
  unsigned blk   = blockIdx.x;
  unsigned row   = blk >> 3;                 // / CH_
  unsigned chunk = blk & (CH_ - 1);
  unsigned bb    = row >> 8;                 // / DEC_
  unsigned q0    = chunk * CW_;
  unsigned qlen  = (chunk == CH_ - 1) ? (V_ - q0) : CW_;   // 6241 on last chunk

  size_t gs  = (size_t)row * V_ + q0;        // global out range [gs, ge)
  size_t ge  = gs + qlen;
  size_t gs4 = gs & ~(size_t)3;
  unsigned phase = (unsigned)(gs - gs4);     // 0..3; LDS idx for global i = i - gs4

  // ---- phase A ----
  if (t < A_) sW[t] = Wa[t];
  if (t == 0) sCnt = 0;
  for (int i = t; i < CW_ + 8; i += 256) sAdd[i] = 0.f;
  __syncthreads();

  float pg = tail[row];

#pragma unroll
  for (int k = 0; k < 4; ++k){
    int e = k * 256 + t;
    unsigned id = (unsigned)ids[bb * ENC_ + e];
    unsigned rel = id - q0;                  // unsigned wrap handles id < q0
    if (rel < qlen){
      int p = atomicAdd(&sCnt, 1);
      sList[p] = (rel << 10) | (unsigned)e;  // rel<6288 (13b) | e (10b)
    }
  }
  __syncthreads();

  // ---- phase B: dots (r7's proven 4-lane pattern) ----
  int cnt = sCnt;
  unsigned lane4 = t & 3u;
  float bav = ba[0];
  float one_m = 1.f - pg;
  size_t rowENC = (size_t)row * ENC_;
  for (int g = t >> 2; g < cnt; g += 64){
    unsigned pk  = sList[g];
    unsigned e   = pk & 1023u;
    unsigned rel = pk >> 10;
    const float4v* ap = reinterpret_cast<const float4v*>(att + (rowENC + e) * A_);
    float acc0 = 0.f, acc1 = 0.f;
#pragma unroll
    for (int j = 0; j < 9; ++j){
      float4v v = ap[lane4 + 4u*j];
      const float* w = &sW[4u*(lane4 + 4u*j)];
      float p = v[0]*w[0] + v[1]*w[1] + v[2]*w[2] + v[3]*w[3];
      if (j & 1) acc1 += p; else acc0 += p;
    }
    float acc = acc0 + acc1;
    acc += __shfl_xor(acc, 1, 64);
    acc += __shfl_xor(acc, 2, 64);
    if (lane4 == 0){
      float x = acc + bav;
      x = x > 0.f ? x : 0.f;
      atomicAdd(&sAdd[rel + phase], one_m * x);   // ds_add_f32
    }
  }
  __syncthreads();

  // ---- phase C: stream chunk ----
  size_t beg4 = (gs + 3) & ~(size_t)3;
  size_t end4 = ge & ~(size_t)3;
  if (t < (int)(beg4 - gs)){ size_t i = gs + t;   out[i] = pg * ovp[i] + sAdd[i - gs4]; }
  if (t < (int)(ge - end4)){ size_t i = end4 + t; out[i] = pg * ovp[i] + sAdd[i - gs4]; }
  const float4v* src = reinterpret_cast<const float4v*>(ovp + beg4);
  float4v*       dst = reinterpret_cast<float4v*>(out + beg4);
  unsigned lbase = (unsigned)(beg4 - gs4);   // multiple of 4
  unsigned n4 = (unsigned)((end4 - beg4) >> 2);
  for (unsigned i = t; i < n4; i += 256){
    float4v a = src[i];
    float4v sa = *reinterpret_cast<const float4v*>(&sAdd[lbase + 4u*i]);
    float4v o;
    o[0] = pg*a[0] + sa[0];
    o[1] = pg*a[1] + sa[1];
    o[2] = pg*a[2] + sa[2];
    o[3] = pg*a[3] + sa[3];
    dst[i] = o;
  }
}

extern "C" void kernel_launch(void* const* d_in, const int* in_sizes, int n_in,
                              void* d_out, int out_size, void* d_ws, size_t ws_size,
                              hipStream_t stream) {
  (void)in_sizes; (void)n_in; (void)d_ws; (void)ws_size; (void)out_size;
  const int*   ids = (const int*)  d_in[0];
  const float* att = (const float*)d_in[1];
  const float* hid = (const float*)d_in[2];
  const float* ovp = (const float*)d_in[3];
  const float* Wp  = (const float*)d_in[4];
  const float* bp  = (const float*)d_in[5];
  const float* Wa  = (const float*)d_in[6];
  const float* ba  = (const float*)d_in[7];
  float* out  = (float*)d_out;
  float* tail = out + (size_t)NROW_ * V_;   // p_gen output (fp32)

  k_pgen <<<NROW_,       256, 0, stream>>>(hid, Wp, bp, tail);
  k_merge<<<NROW_ * CH_, 256, 0, stream>>>(ids, att, ovp, Wa, ba, tail, out);
}

// Round 10
// 199.166 us; speedup vs baseline: 1.2581x; 1.0387x over previous
//
#include <hip/hip_runtime.h>

#define B_    4
#define DEC_  256
#define ENC_  1024
#define D_    1024
#define A_    144
#define V_    50257
#define NROW_ (B_ * DEC_)
#define CH_   16         // vocab chunks per row
#define CW_   3144       // chunk width: 16*3144 = 50304 >= V_, multiple of 8

typedef __attribute__((ext_vector_type(4))) float float4v;

// ---------------- kernel 1: p_gen = sigmoid(hidden . W_pgen + b) -> out tail (fp32) ----------------
__global__ void k_pgen(const float* __restrict__ hid, const float* __restrict__ Wp,
                       const float* __restrict__ bp, float* __restrict__ tail){
  int row = blockIdx.x, t = threadIdx.x;
  float4v hv = reinterpret_cast<const float4v*>(hid + (size_t)row * D_)[t];
  float4v wv = reinterpret_cast<const float4v*>(Wp)[t];
  float s = hv[0]*wv[0] + hv[1]*wv[1] + hv[2]*wv[2] + hv[3]*wv[3];
  for (int o = 32; o > 0; o >>= 1) s += __shfl_down(s, o, 64);
  __shared__ float red[4];
  if ((t & 63) == 0) red[t >> 6] = s;
  __syncthreads();
  if (t == 0){
    float tot = red[0] + red[1] + red[2] + red[3] + bp[0];
    tail[row] = 1.f / (1.f + __expf(-tot));
  }
}

// ---------------- kernel 2: fused scatter + base stream, async ovp staging ----------------
// block = (row, chunk). Phases:
//  A: init LDS; scan row's 1024 ids -> sList of in-chunk entries
//  B: issue global_load_lds staging of ovp chunk -> sOvp (completes under the dots);
//     att-dot for listed e's (4 lanes/e) -> ds_add_f32 into sAdd
//  C: out[chunk] = pg*sOvp + sAdd   (LDS reads + pure coalesced global writes)
__global__ __launch_bounds__(256) void k_merge(const int* __restrict__ ids,
                                               const float* __restrict__ att,
                                               const float* __restrict__ ovp,
                                               const float* __restrict__ Wa,
                                               const float* __restrict__ ba,
                                               const float* __restrict__ tail,
                                               float* __restrict__ out){
  __shared__ float sW[A_];
  __shared__ __align__(16) float sAdd[CW_ + 8];
  __shared__ __align__(16) float sOvp[CW_ + 4];
  __shared__ unsigned sList[ENC_];
  __shared__ int sCnt;

  int t = threadIdx.x;
  unsigned blk   = blockIdx.x;
  unsigned row   = blk >> 4;                  // / CH_
  unsigned chunk = blk & (CH_ - 1);
  unsigned bb    = row >> 8;                  // / DEC_
  unsigned q0    = chunk * CW_;
  unsigned qlen  = (chunk == CH_ - 1) ? (V_ - q0) : CW_;   // 3097 on last chunk

  size_t gs   = (size_t)row * V_ + q0;
  size_t ge   = gs + qlen;
  size_t gs4  = gs & ~(size_t)3;
  size_t beg4 = (gs + 3) & ~(size_t)3;
  size_t end4 = ge & ~(size_t)3;
  unsigned phase = (unsigned)(gs - gs4);      // 0..3
  unsigned lbase = (unsigned)(beg4 - gs4);    // 0 or 4
  unsigned n4    = (unsigned)((end4 - beg4) >> 2);
  int nhead = (int)(beg4 - gs);
  int ntail = (int)(ge - end4);

  // ---- phase A ----
  if (t < A_) sW[t] = Wa[t];
  if (t == 0) sCnt = 0;
  for (int i = t; i < CW_ + 8; i += 256) sAdd[i] = 0.f;
  __syncthreads();

  float pg = tail[row];

#pragma unroll
  for (int k = 0; k < 4; ++k){
    int e = k * 256 + t;
    unsigned id = (unsigned)ids[bb * ENC_ + e];
    unsigned rel = id - q0;                   // unsigned wrap handles id < q0
    if (rel < qlen){
      int p = atomicAdd(&sCnt, 1);
      sList[p] = (rel << 10) | (unsigned)e;   // rel<3144 (12b) | e (10b)
    }
  }
  __syncthreads();

  // ---- phase B: async ovp staging, then att dots ----
  const float4v* src = reinterpret_cast<const float4v*>(ovp + beg4);
  {
    unsigned wave = (unsigned)t >> 6, lane = (unsigned)t & 63u;
    unsigned ncall = (n4 + 63u) >> 6;         // <= 13
    for (unsigned c = wave; c < ncall; c += 4){
      unsigned idx = c * 64u + lane;
      if (idx < n4)
        __builtin_amdgcn_global_load_lds(
            (const unsigned int*)(src + idx),
            (unsigned int*)((char*)sOvp + (size_t)c * 1024),
            16, 0, 0);
    }
  }
  float preH = (t < nhead) ? ovp[gs + t]   : 0.f;
  float preT = (t < ntail) ? ovp[end4 + t] : 0.f;

  int cnt = sCnt;
  unsigned lane4 = (unsigned)t & 3u;
  float bav = ba[0];
  float one_m = 1.f - pg;
  size_t rowENC = (size_t)row * ENC_;
  for (int g = t >> 2; g < cnt; g += 64){
    unsigned pk  = sList[g];
    unsigned e   = pk & 1023u;
    unsigned rel = pk >> 10;
    const float4v* ap = reinterpret_cast<const float4v*>(att + (rowENC + e) * A_);
    float acc0 = 0.f, acc1 = 0.f;
#pragma unroll
    for (int j = 0; j < 9; ++j){
      float4v v = ap[lane4 + 4u*j];
      const float* w = &sW[4u*(lane4 + 4u*j)];
      float p = v[0]*w[0] + v[1]*w[1] + v[2]*w[2] + v[3]*w[3];
      if (j & 1) acc1 += p; else acc0 += p;
    }
    float acc = acc0 + acc1;
    acc += __shfl_xor(acc, 1, 64);
    acc += __shfl_xor(acc, 2, 64);
    if (lane4 == 0){
      float x = acc + bav;
      x = x > 0.f ? x : 0.f;
      atomicAdd(&sAdd[rel + phase], one_m * x);   // ds_add_f32
    }
  }
  __syncthreads();   // sAdd complete; vmcnt(0) drain completes sOvp staging

  // ---- phase C: stream chunk (LDS -> global, write-only traffic) ----
  if (t < nhead) out[gs + t]   = pg * preH + sAdd[phase + (unsigned)t];
  if (t < ntail) out[end4 + t] = pg * preT + sAdd[lbase + 4u*n4 + (unsigned)t];
  float4v* dst = reinterpret_cast<float4v*>(out + beg4);
  const float4v* sOvpV = reinterpret_cast<const float4v*>(sOvp);
  for (unsigned i = t; i < n4; i += 256){
    float4v a  = sOvpV[i];
    float4v sa = *reinterpret_cast<const float4v*>(&sAdd[lbase + 4u*i]);
    float4v o;
    o[0] = pg*a[0] + sa[0];
    o[1] = pg*a[1] + sa[1];
    o[2] = pg*a[2] + sa[2];
    o[3] = pg*a[3] + sa[3];
    dst[i] = o;
  }
}

extern "C" void kernel_launch(void* const* d_in, const int* in_sizes, int n_in,
                              void* d_out, int out_size, void* d_ws, size_t ws_size,
                              hipStream_t stream) {
  (void)in_sizes; (void)n_in; (void)d_ws; (void)ws_size; (void)out_size;
  const int*   ids = (const int*)  d_in[0];
  const float* att = (const float*)d_in[1];
  const float* hid = (const float*)d_in[2];
  const float* ovp = (const float*)d_in[3];
  const float* Wp  = (const float*)d_in[4];
  const float* bp  = (const float*)d_in[5];
  const float* Wa  = (const float*)d_in[6];
  const float* ba  = (const float*)d_in[7];
  float* out  = (float*)d_out;
  float* tail = out + (size_t)NROW_ * V_;   // p_gen output (fp32)

  k_pgen <<<NROW_,       256, 0, stream>>>(hid, Wp, bp, tail);
  k_merge<<<NROW_ * CH_, 256, 0, stream>>>(ids, att, ovp, Wa, ba, tail, out);
}

// Round 11
// 188.524 us; speedup vs baseline: 1.3291x; 1.0564x over previous
//
#include <hip/hip_runtime.h>

#define B_    4
#define DEC_  256
#define ENC_  1024
#define D_    1024
#define A_    144
#define V_    50257
#define NROW_ (B_ * DEC_)
#define CH_   16         // vocab chunks per row
#define CW_   3144       // chunk width: 16*3144 = 50304 >= V_, multiple of 8

typedef __attribute__((ext_vector_type(4))) float float4v;

// ---------------- single fused kernel ----------------
// block = (row, chunk). Phases:
//  A: init LDS (vec zero sAdd); p_gen dot (redundant per block, deterministic);
//     scan row's 1024 ids -> sList of in-chunk entries
//  B: issue global_load_lds staging of ovp chunk -> sOvp (hides under the dots);
//     att-dot for listed e's (4 lanes/e) -> ds_add_f32 into sAdd
//  C: out[chunk] = pg*sOvp + sAdd   (LDS reads + nontemporal coalesced writes)
__global__ __launch_bounds__(256) void k_merge(const int* __restrict__ ids,
                                               const float* __restrict__ att,
                                               const float* __restrict__ hid,
                                               const float* __restrict__ ovp,
                                               const float* __restrict__ Wp,
                                               const float* __restrict__ bp,
                                               const float* __restrict__ Wa,
                                               const float* __restrict__ ba,
                                               float* __restrict__ out,
                                               float* __restrict__ tail){
  __shared__ float sW[A_];
  __shared__ float red[4];
  __shared__ __align__(16) float sAdd[CW_ + 8];
  __shared__ __align__(16) float sOvp[CW_ + 4];
  __shared__ unsigned sList[ENC_];
  __shared__ int sCnt;

  int t = threadIdx.x;
  unsigned blk   = blockIdx.x;
  unsigned row   = blk >> 4;                  // / CH_
  unsigned chunk = blk & (CH_ - 1);
  unsigned bb    = row >> 8;                  // / DEC_
  unsigned q0    = chunk * CW_;
  unsigned qlen  = (chunk == CH_ - 1) ? (V_ - q0) : CW_;   // 3097 on last chunk

  size_t gs   = (size_t)row * V_ + q0;
  size_t ge   = gs + qlen;
  size_t gs4  = gs & ~(size_t)3;
  size_t beg4 = (gs + 3) & ~(size_t)3;
  size_t end4 = ge & ~(size_t)3;
  unsigned phase = (unsigned)(gs - gs4);      // 0..3
  unsigned lbase = (unsigned)(beg4 - gs4);    // 0 or 4
  unsigned n4    = (unsigned)((end4 - beg4) >> 2);
  int nhead = (int)(beg4 - gs);
  int ntail = (int)(ge - end4);

  // ---- phase A: init + p_gen dot ----
  if (t < A_) sW[t] = Wa[t];
  if (t == 0) sCnt = 0;
  {
    float4v z; z[0] = 0.f; z[1] = 0.f; z[2] = 0.f; z[3] = 0.f;
    float4v* za = reinterpret_cast<float4v*>(sAdd);
    for (int i = t; i < (CW_ + 8) / 4; i += 256) za[i] = z;
  }
  {
    float4v hv = reinterpret_cast<const float4v*>(hid + (size_t)row * D_)[t];
    float4v wv = reinterpret_cast<const float4v*>(Wp)[t];
    float s = hv[0]*wv[0] + hv[1]*wv[1] + hv[2]*wv[2] + hv[3]*wv[3];
    for (int o = 32; o > 0; o >>= 1) s += __shfl_down(s, o, 64);
    if ((t & 63) == 0) red[t >> 6] = s;
  }
  __syncthreads();
  float pg = 1.f / (1.f + __expf(-(red[0] + red[1] + red[2] + red[3] + bp[0])));
  if (chunk == 0 && t == 0) tail[row] = pg;

#pragma unroll
  for (int k = 0; k < 4; ++k){
    int e = k * 256 + t;
    unsigned id = (unsigned)ids[bb * ENC_ + e];
    unsigned rel = id - q0;                   // unsigned wrap handles id < q0
    if (rel < qlen){
      int p = atomicAdd(&sCnt, 1);
      sList[p] = (rel << 10) | (unsigned)e;   // rel<3144 (12b) | e (10b)
    }
  }
  __syncthreads();

  // ---- phase B: async ovp staging, then att dots ----
  const float4v* src = reinterpret_cast<const float4v*>(ovp + beg4);
  {
    unsigned wave = (unsigned)t >> 6, lane = (unsigned)t & 63u;
    unsigned ncall = (n4 + 63u) >> 6;         // <= 13
    for (unsigned c = wave; c < ncall; c += 4){
      unsigned idx = c * 64u + lane;
      if (idx < n4)
        __builtin_amdgcn_global_load_lds(
            (const unsigned int*)(src + idx),
            (unsigned int*)((char*)sOvp + (size_t)c * 1024),
            16, 0, 0);
    }
  }
  float preH = (t < nhead) ? ovp[gs + t]   : 0.f;
  float preT = (t < ntail) ? ovp[end4 + t] : 0.f;

  int cnt = sCnt;
  unsigned lane4 = (unsigned)t & 3u;
  float bav = ba[0];
  float one_m = 1.f - pg;
  size_t rowENC = (size_t)row * ENC_;
  for (int g = t >> 2; g < cnt; g += 64){
    unsigned pk  = sList[g];
    unsigned e   = pk & 1023u;
    unsigned rel = pk >> 10;
    const float4v* ap = reinterpret_cast<const float4v*>(att + (rowENC + e) * A_);
    float acc0 = 0.f, acc1 = 0.f;
#pragma unroll
    for (int j = 0; j < 9; ++j){
      float4v v = ap[lane4 + 4u*j];
      const float* w = &sW[4u*(lane4 + 4u*j)];
      float p = v[0]*w[0] + v[1]*w[1] + v[2]*w[2] + v[3]*w[3];
      if (j & 1) acc1 += p; else acc0 += p;
    }
    float acc = acc0 + acc1;
    acc += __shfl_xor(acc, 1, 64);
    acc += __shfl_xor(acc, 2, 64);
    if (lane4 == 0){
      float x = acc + bav;
      x = x > 0.f ? x : 0.f;
      atomicAdd(&sAdd[rel + phase], one_m * x);   // ds_add_f32
    }
  }
  __syncthreads();   // sAdd complete; vmcnt(0) drain completes sOvp staging

  // ---- phase C: stream chunk (LDS -> global, nontemporal writes) ----
  if (t < nhead) __builtin_nontemporal_store(pg * preH + sAdd[phase + (unsigned)t], &out[gs + t]);
  if (t < ntail) __builtin_nontemporal_store(pg * preT + sAdd[lbase + 4u*n4 + (unsigned)t], &out[end4 + t]);
  float4v* dst = reinterpret_cast<float4v*>(out + beg4);
  const float4v* sOvpV = reinterpret_cast<const float4v*>(sOvp);
  for (unsigned i = t; i < n4; i += 256){
    float4v a  = sOvpV[i];
    float4v sa = *reinterpret_cast<const float4v*>(&sAdd[lbase + 4u*i]);
    float4v o;
    o[0] = pg*a[0] + sa[0];
    o[1] = pg*a[1] + sa[1];
    o[2] = pg*a[2] + sa[2];
    o[3] = pg*a[3] + sa[3];
    __builtin_nontemporal_store(o, &dst[i]);
  }
}

extern "C" void kernel_launch(void* const* d_in, const int* in_sizes, int n_in,
                              void* d_out, int out_size, void* d_ws, size_t ws_size,
                              hipStream_t stream) {
  (void)in_sizes; (void)n_in; (void)d_ws; (void)ws_size; (void)out_size;
  const int*   ids = (const int*)  d_in[0];
  const float* att = (const float*)d_in[1];
  const float* hid = (const float*)d_in[2];
  const float* ovp = (const float*)d_in[3];
  const float* Wp  = (const float*)d_in[4];
  const float* bp  = (const float*)d_in[5];
  const float* Wa  = (const float*)d_in[6];
  const float* ba  = (const float*)d_in[7];
  float* out  = (float*)d_out;
  float* tail = out + (size_t)NROW_ * V_;   // p_gen output (fp32)

  k_merge<<<NROW_ * CH_, 256, 0, stream>>>(ids, att, hid, ovp, Wp, bp, Wa, ba, out, tail);
}